// Round 7
// baseline (119.459 us; speedup 1.0000x reference)
//
#include <hip/hip_runtime.h>
#include <hip/hip_bf16.h>
#include <stdint.h>

#define M_DIM 8192
#define N_DIM 1024
#define K_DIM 4096

typedef __bf16 bf16x8 __attribute__((ext_vector_type(8)));
typedef float f32x4 __attribute__((ext_vector_type(4)));
typedef __hip_bfloat16 bf16_t;

__device__ __forceinline__ void gload_lds16(const void* g, void* l) {
  __builtin_amdgcn_global_load_lds(
      (const __attribute__((address_space(1))) void*)g,
      (__attribute__((address_space(3))) void*)l, 16, 0, 0);
}

// ---- pack: fp32 [R][4096] -> bf16 tiled [rt][kt][256 rows][8 chunks], with
// st-swizzle pre-applied (chunk' = chunk ^ (row&7)); enc+W in one launch.
__global__ __launch_bounds__(256) void pack_both(const float* __restrict__ enc,
                                                 const float* __restrict__ W,
                                                 int4* __restrict__ pA,
                                                 int4* __restrict__ pB) {
  const unsigned gtid = blockIdx.x * 256 + threadIdx.x;
  const float* src;
  int4* dst;
  unsigned t;
  if (gtid < 4194304u) { src = enc; dst = pA; t = gtid; }          // 8192*4096/8
  else                 { src = W;   dst = pB; t = gtid - 4194304u; }
  const unsigned cp = t & 7;
  const unsigned tmp = t >> 3;
  const unsigned r = tmp & 255;
  const unsigned tmp2 = tmp >> 8;
  const unsigned kt = tmp2 & 63;
  const unsigned rt = tmp2 >> 6;
  const unsigned srow = (rt << 8) + r;
  const unsigned k0 = (kt << 6) + ((cp ^ (r & 7)) << 3);
  const float4* s = (const float4*)(src + (size_t)srow * 4096 + k0);
  float4 a = s[0], b = s[1];
  union { bf16_t h[8]; int4 v; } u;
  u.h[0] = __float2bfloat16(a.x); u.h[1] = __float2bfloat16(a.y);
  u.h[2] = __float2bfloat16(a.z); u.h[3] = __float2bfloat16(a.w);
  u.h[4] = __float2bfloat16(b.x); u.h[5] = __float2bfloat16(b.y);
  u.h[6] = __float2bfloat16(b.z); u.h[7] = __float2bfloat16(b.w);
  dst[t] = u.v;
}

// ---- 8-phase 256x256 GEMM, PIPELINED ds_reads (r7) ---------------------------
// 512 thr = 8 waves (2M x 4N), per-wave C = 128x64. All staging via
// global_load_lds from pre-swizzled packed bf16. Key change vs r3: operand
// ds_reads are issued ONE PHASE BEFORE their MFMA, so LDS service overlaps the
// previous MFMA cluster instead of serializing (r3's structure was
// reads -> barrier -> lgkm0 -> MFMA = fully serial, measured ~69 us).
// Quadrants: P0=M0N0(aE,b0) P1=M0N1(aE,b1) P2=M1N1(aO,b1) P3=M1N0(aO,b0).
// Read issue: P0: b1(g)[4]; P1: aO(g)[8]; P2: aE(g+1)[8]; P3-tail: b0(g+1)[4].
// Stages: P0: Bh0(g+1),Ah1(g+1); P2: Bh1(g+1),Ah0(g+2).
// vmcnt ledger (FIFO, entry invariant [Ah0(g+1)x2]):
//   P1-end vmcnt(2): retires Ah0(g+1),Bh0(g+1) -> aE/b0 slots readable
//   P2-end vmcnt(4): retires Ah1(g+1)          -> aO slot readable next tile
//   P3-end vmcnt(2): retires Bh1(g+1)          -> b1 slot readable next tile
// ONE barrier per phase (each slot has >=1 full phase between last reader's
// lgkm gate and its overwrite; cross-wave safety via vmcnt-before-barrier).
__device__ __forceinline__ void stage_half(const char* g, char* smem, int ldsoff, int tid) {
  gload_lds16(g + tid * 16, smem + ldsoff + tid * 16);
  gload_lds16(g + 8192 + tid * 16, smem + ldsoff + 8192 + tid * 16);
}

__global__ __launch_bounds__(512, 2) void gemm8(
    const char* __restrict__ pA, const char* __restrict__ pB,
    float* __restrict__ V0, float* __restrict__ V1p, int NT) {
  extern __shared__ char smem[];
  const int tid = threadIdx.x;
  const int lane = tid & 63, wave = tid >> 6;
  const int wm = wave >> 2, wn = wave & 3;
  const int lrow = lane & 15, lkc = lane >> 4;

  // XCD-aware swizzle (grid 128/256 -> %8==0, bijective)
  const int cpx = (int)gridDim.x >> 3;
  const int swz = ((int)blockIdx.x & 7) * cpx + ((int)blockIdx.x >> 3);
  const int split = swz >> 7;
  const int rem = swz & 127;
  const int mt = rem >> 2, nt = rem & 3;

  const char* Abase = pA + ((size_t)mt * 64 + (size_t)split * NT) * 32768;
  const char* Bbase = pB + ((size_t)nt * 64 + (size_t)split * NT) * 32768;
  float* V = split ? V1p : V0;

  // Swizzle folds to per-lane constants ((row&7)==(lrow&7) for all frag rows).
  int colw[2];
  colw[0] = ((lkc) ^ (lrow & 7)) << 4;
  colw[1] = ((4 + lkc) ^ (lrow & 7)) << 4;
  int aRow[4], bRow[2];
  #pragma unroll
  for (int f = 0; f < 4; ++f) aRow[f] = (wm * 64 + f * 16 + lrow) * 128;
  #pragma unroll
  for (int f2 = 0; f2 < 2; ++f2) bRow[f2] = 32768 + (wn * 32 + f2 * 16 + lrow) * 128;

  f32x4 acc[2][4][2][2];
  #pragma unroll
  for (int a0 = 0; a0 < 2; ++a0)
    #pragma unroll
    for (int a1 = 0; a1 < 4; ++a1)
      #pragma unroll
      for (int a2 = 0; a2 < 2; ++a2)
        #pragma unroll
        for (int a3 = 0; a3 < 2; ++a3)
          acc[a0][a1][a2][a3] = (f32x4){0.f, 0.f, 0.f, 0.f};

  const int ktm = NT - 1;

  // ---- Prologue: stage all 4 tile-0 slots + Ah0(1); retire tile-0 (vmcnt(2)
  // leaves [Ah0(1)x2] = loop entry invariant); pre-read aE(0), b0(0).
  stage_half(Abase,         smem, 0, tid);       // Ah0(0)
  stage_half(Abase + 16384, smem, 16384, tid);   // Ah1(0)
  stage_half(Bbase,         smem, 32768, tid);   // Bh0(0)
  stage_half(Bbase + 16384, smem, 49152, tid);   // Bh1(0)
  stage_half(Abase + 32768, smem, 65536, tid);   // Ah0(1)
  asm volatile("s_waitcnt vmcnt(2)" ::: "memory");
  __builtin_amdgcn_sched_barrier(0);
  __builtin_amdgcn_s_barrier();

  bf16x8 aE[4][2], aO[4][2], b0[2][2], b1[2][2];
  #pragma unroll
  for (int f = 0; f < 4; ++f)
    #pragma unroll
    for (int s = 0; s < 2; ++s)
      aE[f][s] = *(const bf16x8*)(smem + aRow[f] + colw[s]);
  #pragma unroll
  for (int f2 = 0; f2 < 2; ++f2)
    #pragma unroll
    for (int s = 0; s < 2; ++s)
      b0[f2][s] = *(const bf16x8*)(smem + bRow[f2] + colw[s]);

  for (int g = 0; g < NT; ++g) {
    const int bb = g & 1, nbf = bb ^ 1;
    char* ab = smem + bb * 65536;
    char* nb = smem + nbf * 65536;
    const char* A1t = Abase + (size_t)((g + 1) & ktm) * 32768;
    const char* B1t = Bbase + (size_t)((g + 1) & ktm) * 32768;
    const char* A2t = Abase + (size_t)((g + 2) & ktm) * 32768;

    // ---- P0: MFMA M0N0; head: read b1(g), stage Bh0(g+1)+Ah1(g+1) ----------
    #pragma unroll
    for (int f2 = 0; f2 < 2; ++f2)
      #pragma unroll
      for (int s = 0; s < 2; ++s)
        b1[f2][s] = *(const bf16x8*)(ab + bRow[f2] + 16384 + colw[s]);
    stage_half(B1t, smem, nbf * 65536 + 32768, tid);          // Bh0(g+1)
    stage_half(A1t + 16384, smem, nbf * 65536 + 16384, tid);  // Ah1(g+1)
    __builtin_amdgcn_s_setprio(1);
    #pragma unroll
    for (int f = 0; f < 4; ++f)
      #pragma unroll
      for (int f2 = 0; f2 < 2; ++f2)
        #pragma unroll
        for (int s = 0; s < 2; ++s)
          acc[0][f][0][f2] = __builtin_amdgcn_mfma_f32_16x16x32_bf16(
              aE[f][s], b0[f2][s], acc[0][f][0][f2], 0, 0, 0);
    __builtin_amdgcn_s_setprio(0);
    __builtin_amdgcn_sched_barrier(0);
    __builtin_amdgcn_s_barrier();

    // ---- P1: MFMA M0N1; head: read aO(g); end vmcnt(2) ---------------------
    #pragma unroll
    for (int f = 0; f < 4; ++f)
      #pragma unroll
      for (int s = 0; s < 2; ++s)
        aO[f][s] = *(const bf16x8*)(ab + aRow[f] + 16384 + colw[s]);
    __builtin_amdgcn_s_setprio(1);
    #pragma unroll
    for (int f = 0; f < 4; ++f)
      #pragma unroll
      for (int f2 = 0; f2 < 2; ++f2)
        #pragma unroll
        for (int s = 0; s < 2; ++s)
          acc[0][f][1][f2] = __builtin_amdgcn_mfma_f32_16x16x32_bf16(
              aE[f][s], b1[f2][s], acc[0][f][1][f2], 0, 0, 0);
    __builtin_amdgcn_s_setprio(0);
    asm volatile("s_waitcnt vmcnt(2)" ::: "memory");
    __builtin_amdgcn_sched_barrier(0);
    __builtin_amdgcn_s_barrier();

    // ---- P2: MFMA M1N1; head: read aE(g+1), stage Bh1(g+1)+Ah0(g+2);
    //      end vmcnt(4) ------------------------------------------------------
    #pragma unroll
    for (int f = 0; f < 4; ++f)
      #pragma unroll
      for (int s = 0; s < 2; ++s)
        aE[f][s] = *(const bf16x8*)(nb + aRow[f] + colw[s]);
    stage_half(B1t + 16384, smem, nbf * 65536 + 49152, tid);  // Bh1(g+1)
    stage_half(A2t, smem, bb * 65536, tid);                   // Ah0(g+2)
    __builtin_amdgcn_s_setprio(1);
    #pragma unroll
    for (int f = 0; f < 4; ++f)
      #pragma unroll
      for (int f2 = 0; f2 < 2; ++f2)
        #pragma unroll
        for (int s = 0; s < 2; ++s)
          acc[1][f][1][f2] = __builtin_amdgcn_mfma_f32_16x16x32_bf16(
              aO[f][s], b1[f2][s], acc[1][f][1][f2], 0, 0, 0);
    __builtin_amdgcn_s_setprio(0);
    asm volatile("s_waitcnt vmcnt(4)" ::: "memory");
    __builtin_amdgcn_sched_barrier(0);
    __builtin_amdgcn_s_barrier();

    // ---- P3: MFMA M1N0; tail: read b0(g+1) (after MFMA, SB-pinned);
    //      end vmcnt(2) ------------------------------------------------------
    __builtin_amdgcn_s_setprio(1);
    #pragma unroll
    for (int f = 0; f < 4; ++f)
      #pragma unroll
      for (int f2 = 0; f2 < 2; ++f2)
        #pragma unroll
        for (int s = 0; s < 2; ++s)
          acc[1][f][0][f2] = __builtin_amdgcn_mfma_f32_16x16x32_bf16(
              aO[f][s], b0[f2][s], acc[1][f][0][f2], 0, 0, 0);
    __builtin_amdgcn_s_setprio(0);
    __builtin_amdgcn_sched_barrier(0);
    #pragma unroll
    for (int f2 = 0; f2 < 2; ++f2)
      #pragma unroll
      for (int s = 0; s < 2; ++s)
        b0[f2][s] = *(const bf16x8*)(nb + bRow[f2] + colw[s]);
    asm volatile("s_waitcnt vmcnt(2)" ::: "memory");
    __builtin_amdgcn_sched_barrier(0);
    __builtin_amdgcn_s_barrier();
  }

  // C-write: frag layout col=lane&15, row=(lane>>4)*4+reg (m89-verified).
  const int lq = lane >> 4;
  #pragma unroll
  for (int qm = 0; qm < 2; ++qm)
    #pragma unroll
    for (int f = 0; f < 4; ++f) {
      const int rowg = mt * 256 + qm * 128 + wm * 64 + f * 16 + lq * 4;
      #pragma unroll
      for (int reg = 0; reg < 4; ++reg) {
        float* Vr = V + (size_t)(rowg + reg) * N_DIM + nt * 256 + wn * 32 + lrow;
        #pragma unroll
        for (int qn = 0; qn < 2; ++qn)
          #pragma unroll
          for (int f2 = 0; f2 < 2; ++f2)
            Vr[qn * 128 + f2 * 16] = acc[qm][f][qn][f2][reg];
      }
    }
}

// ---- Householder epilogue: combines split-K partials, in-place on d_out ------
__global__ __launch_bounds__(256) void householder_ep(
    const float* __restrict__ x, const float* __restrict__ bias,
    float* __restrict__ vio, const float* __restrict__ V2,
    float* __restrict__ logdet) {
  const int row = blockIdx.x;
  const int t = threadIdx.x;
  float4* vr = (float4*)(vio + (size_t)row * N_DIM);
  const float4* xr = (const float4*)(x + (size_t)row * N_DIM);
  const float4* br = (const float4*)bias;

  float4 v = vr[t];
  if (V2) {
    float4 v2 = ((const float4*)(V2 + (size_t)row * N_DIM))[t];
    v.x += v2.x; v.y += v2.y; v.z += v2.z; v.w += v2.w;
  }
  float4 bb = br[t];
  v.x += bb.x; v.y += bb.y; v.z += bb.z; v.w += bb.w;
  float4 xx = xr[t];

  float dot = v.x * xx.x + v.y * xx.y + v.z * xx.z + v.w * xx.w;
  float nsq = v.x * v.x + v.y * v.y + v.z * v.z + v.w * v.w;

  #pragma unroll
  for (int off = 32; off > 0; off >>= 1) {
    dot += __shfl_down(dot, off);
    nsq += __shfl_down(nsq, off);
  }
  __shared__ float sd[4], sn[4];
  if ((t & 63) == 0) { sd[t >> 6] = dot; sn[t >> 6] = nsq; }
  __syncthreads();
  dot = sd[0] + sd[1] + sd[2] + sd[3];
  nsq = sn[0] + sn[1] + sn[2] + sn[3];

  const float f = 2.0f * dot / sqrtf(nsq);
  float4 o;
  o.x = xx.x - f * v.x;
  o.y = xx.y - f * v.y;
  o.z = xx.z - f * v.z;
  o.w = xx.w - f * v.w;
  vr[t] = o;
  if (t == 0) logdet[row] = 0.0f;
}

extern "C" void kernel_launch(void* const* d_in, const int* in_sizes, int n_in,
                              void* d_out, int out_size, void* d_ws, size_t ws_size,
                              hipStream_t stream) {
  const float* x   = (const float*)d_in[0];   // [8192,1024]
  const float* enc = (const float*)d_in[1];   // [8192,4096]
  const float* W   = (const float*)d_in[2];   // [1024,4096]
  const float* b   = (const float*)d_in[3];   // [1024]

  float* out    = (float*)d_out;
  float* v      = out;                              // V partial 0 lives in d_out
  float* logdet = out + (size_t)M_DIM * N_DIM;

  char*  packA = (char*)d_ws;                       // 64 MB
  char*  packB = packA + (size_t)64 * 1024 * 1024;  //  8 MB
  float* V2    = (float*)(packB + (size_t)8 * 1024 * 1024);  // 32 MB

  const size_t need2 = (size_t)104 * 1024 * 1024;
  const int nsplit = (ws_size >= need2) ? 2 : 1;

  pack_both<<<18432, 256, 0, stream>>>(enc, W, (int4*)packA, (int4*)packB);

  hipFuncSetAttribute((const void*)gemm8, hipFuncAttributeMaxDynamicSharedMemorySize, 131072);
  gemm8<<<dim3(128 * nsplit), 512, 131072, stream>>>(
      packA, packB, v, nsplit == 2 ? V2 : nullptr, 64 / nsplit);

  householder_ep<<<M_DIM, 256, 0, stream>>>(x, b, v, nsplit == 2 ? V2 : nullptr, logdet);
}